// Round 1
// baseline (117.427 us; speedup 1.0000x reference)
//
#include <hip/hip_runtime.h>

#define NDEPTH 8
#define DDIM 2048
#define THREADS 256
#define EPS 1e-6f

// One block per (b,t). Each thread holds all 8 depth rows' data for its
// 8 d-elements (2 float4 slots) in registers, so V is read exactly once.
__global__ __launch_bounds__(THREADS)
void block_attn_residual_kernel(const float* __restrict__ V,
                                const float* __restrict__ wn,
                                const float* __restrict__ pq,
                                float* __restrict__ out,
                                int BT) {
    const int bt  = blockIdx.x;
    const int tid = threadIdx.x;

    // float4 slot indices into the D=2048 row (512 float4 slots, 256 threads)
    const int f0 = tid;
    const int f1 = tid + THREADS;

    // wq[d] = key_norm_weight[d] * pseudo_query[d] (folded: logit = rms * dot(V, wq))
    const float4* w4 = reinterpret_cast<const float4*>(wn);
    const float4* q4 = reinterpret_cast<const float4*>(pq);
    float4 wq0, wq1;
    {
        float4 a = w4[f0], b = q4[f0];
        wq0 = make_float4(a.x * b.x, a.y * b.y, a.z * b.z, a.w * b.w);
        float4 c = w4[f1], e = q4[f1];
        wq1 = make_float4(c.x * e.x, c.y * e.y, c.z * e.z, c.w * e.w);
    }

    // V[n,b,t,d] flat index = (n*BT + bt)*D + d
    const float4* V4 = reinterpret_cast<const float4*>(V) + (size_t)bt * (DDIM / 4);
    const size_t nStride = (size_t)BT * (DDIM / 4);  // float4 stride between depth entries

    float4 v[NDEPTH][2];
    float ss[NDEPTH];   // sum of squares partial
    float dt[NDEPTH];   // dot with wq partial

#pragma unroll
    for (int n = 0; n < NDEPTH; ++n) {
        float4 a = V4[(size_t)n * nStride + f0];
        float4 b = V4[(size_t)n * nStride + f1];
        v[n][0] = a;
        v[n][1] = b;
        ss[n] = a.x * a.x + a.y * a.y + a.z * a.z + a.w * a.w
              + b.x * b.x + b.y * b.y + b.z * b.z + b.w * b.w;
        dt[n] = a.x * wq0.x + a.y * wq0.y + a.z * wq0.z + a.w * wq0.w
              + b.x * wq1.x + b.y * wq1.y + b.z * wq1.z + b.w * wq1.w;
    }

    // 64-lane butterfly reduction for the 16 partials
#pragma unroll
    for (int n = 0; n < NDEPTH; ++n) {
#pragma unroll
        for (int off = 32; off > 0; off >>= 1) {
            ss[n] += __shfl_xor(ss[n], off, 64);
            dt[n] += __shfl_xor(dt[n], off, 64);
        }
    }

    // cross-wave reduce (4 waves) via tiny LDS buffer
    __shared__ float red_ss[4][NDEPTH];
    __shared__ float red_dt[4][NDEPTH];
    const int wave = tid >> 6;
    const int lane = tid & 63;
    if (lane == 0) {
#pragma unroll
        for (int n = 0; n < NDEPTH; ++n) {
            red_ss[wave][n] = ss[n];
            red_dt[wave][n] = dt[n];
        }
    }
    __syncthreads();

    // every thread computes the 8 logits + softmax redundantly (wave-uniform)
    float logit[NDEPTH];
    float m = -INFINITY;
#pragma unroll
    for (int n = 0; n < NDEPTH; ++n) {
        float S = red_ss[0][n] + red_ss[1][n] + red_ss[2][n] + red_ss[3][n];
        float Dq = red_dt[0][n] + red_dt[1][n] + red_dt[2][n] + red_dt[3][n];
        float rms = rsqrtf(S * (1.0f / DDIM) + EPS);
        logit[n] = rms * Dq;
        m = fmaxf(m, logit[n]);
    }
    float wgt[NDEPTH];
    float denom = 0.0f;
#pragma unroll
    for (int n = 0; n < NDEPTH; ++n) {
        wgt[n] = __expf(logit[n] - m);
        denom += wgt[n];
    }
    const float inv = 1.0f / denom;

    float4 o0 = make_float4(0.f, 0.f, 0.f, 0.f);
    float4 o1 = make_float4(0.f, 0.f, 0.f, 0.f);
#pragma unroll
    for (int n = 0; n < NDEPTH; ++n) {
        const float wn_ = wgt[n] * inv;
        o0.x += wn_ * v[n][0].x;
        o0.y += wn_ * v[n][0].y;
        o0.z += wn_ * v[n][0].z;
        o0.w += wn_ * v[n][0].w;
        o1.x += wn_ * v[n][1].x;
        o1.y += wn_ * v[n][1].y;
        o1.z += wn_ * v[n][1].z;
        o1.w += wn_ * v[n][1].w;
    }

    float4* out4 = reinterpret_cast<float4*>(out) + (size_t)bt * (DDIM / 4);
    out4[f0] = o0;
    out4[f1] = o1;
}

extern "C" void kernel_launch(void* const* d_in, const int* in_sizes, int n_in,
                              void* d_out, int out_size, void* d_ws, size_t ws_size,
                              hipStream_t stream) {
    const float* V  = (const float*)d_in[0];
    const float* wn = (const float*)d_in[1];
    const float* pq = (const float*)d_in[2];
    float* out = (float*)d_out;

    const int BT = in_sizes[0] / (NDEPTH * DDIM);  // B*T
    block_attn_residual_kernel<<<dim3(BT), dim3(THREADS), 0, stream>>>(V, wn, pq, out, BT);
}

// Round 2
// 105.821 us; speedup vs baseline: 1.1097x; 1.1097x over previous
//
#include <hip/hip_runtime.h>

#define NDEPTH 8
#define DDIM 2048
#define THREADS 512
#define EPS 1e-6f

typedef float f32x4 __attribute__((ext_vector_type(4)));

// One block per (b,t); 512 threads, each owns exactly one float4 slot of the
// D=2048 row for all 8 depth entries (32 VGPRs of V data). V streams through
// registers exactly once; non-temporal hints keep it out of the caches.
__global__ __launch_bounds__(THREADS)
void block_attn_residual_kernel(const float* __restrict__ V,
                                const float* __restrict__ wn,
                                const float* __restrict__ pq,
                                float* __restrict__ out,
                                int BT) {
    const int bt  = blockIdx.x;
    const int tid = threadIdx.x;
    const int f   = tid;                 // float4 slot 0..511

    // wq[d] = key_norm_weight[d] * pseudo_query[d]
    const f32x4* w4 = reinterpret_cast<const f32x4*>(wn);
    const f32x4* q4 = reinterpret_cast<const f32x4*>(pq);
    const f32x4 wv = w4[f];
    const f32x4 qv = q4[f];
    const f32x4 wq = wv * qv;

    // V[n,b,t,d] flat index = (n*BT + bt)*D + d
    const f32x4* V4 = reinterpret_cast<const f32x4*>(V) + (size_t)bt * (DDIM / 4);
    const size_t nStride = (size_t)BT * (DDIM / 4);

    f32x4 v[NDEPTH];
    float ss[NDEPTH];   // sum-of-squares partials
    float dt[NDEPTH];   // dot-with-wq partials

#pragma unroll
    for (int n = 0; n < NDEPTH; ++n) {
        f32x4 x = __builtin_nontemporal_load(&V4[(size_t)n * nStride + f]);
        v[n] = x;
        ss[n] = x[0]*x[0] + x[1]*x[1] + x[2]*x[2] + x[3]*x[3];
        dt[n] = x[0]*wq[0] + x[1]*wq[1] + x[2]*wq[2] + x[3]*wq[3];
    }

    // 64-lane butterfly reduction of the 16 per-thread partials
#pragma unroll
    for (int n = 0; n < NDEPTH; ++n) {
#pragma unroll
        for (int off = 32; off > 0; off >>= 1) {
            ss[n] += __shfl_xor(ss[n], off, 64);
            dt[n] += __shfl_xor(dt[n], off, 64);
        }
    }

    // cross-wave reduce (8 waves) via tiny LDS buffer
    __shared__ float red_ss[8][NDEPTH];
    __shared__ float red_dt[8][NDEPTH];
    const int wave = tid >> 6;
    const int lane = tid & 63;
    if (lane == 0) {
#pragma unroll
        for (int n = 0; n < NDEPTH; ++n) {
            red_ss[wave][n] = ss[n];
            red_dt[wave][n] = dt[n];
        }
    }
    __syncthreads();

    // every thread computes the 8 logits + softmax redundantly (wave-uniform)
    float logit[NDEPTH];
    float m = -INFINITY;
#pragma unroll
    for (int n = 0; n < NDEPTH; ++n) {
        float S = 0.0f, Dq = 0.0f;
#pragma unroll
        for (int w = 0; w < 8; ++w) {
            S  += red_ss[w][n];
            Dq += red_dt[w][n];
        }
        float rms = rsqrtf(S * (1.0f / DDIM) + EPS);
        logit[n] = rms * Dq;
        m = fmaxf(m, logit[n]);
    }
    float wgt[NDEPTH];
    float denom = 0.0f;
#pragma unroll
    for (int n = 0; n < NDEPTH; ++n) {
        wgt[n] = __expf(logit[n] - m);
        denom += wgt[n];
    }
    const float inv = 1.0f / denom;

    f32x4 o = {0.0f, 0.0f, 0.0f, 0.0f};
#pragma unroll
    for (int n = 0; n < NDEPTH; ++n) {
        const float wn_ = wgt[n] * inv;
        o[0] += wn_ * v[n][0];
        o[1] += wn_ * v[n][1];
        o[2] += wn_ * v[n][2];
        o[3] += wn_ * v[n][3];
    }

    f32x4* out4 = reinterpret_cast<f32x4*>(out) + (size_t)bt * (DDIM / 4);
    __builtin_nontemporal_store(o, &out4[f]);
}

extern "C" void kernel_launch(void* const* d_in, const int* in_sizes, int n_in,
                              void* d_out, int out_size, void* d_ws, size_t ws_size,
                              hipStream_t stream) {
    const float* V  = (const float*)d_in[0];
    const float* wn = (const float*)d_in[1];
    const float* pq = (const float*)d_in[2];
    float* out = (float*)d_out;

    const int BT = in_sizes[0] / (NDEPTH * DDIM);  // B*T
    block_attn_residual_kernel<<<dim3(BT), dim3(THREADS), 0, stream>>>(V, wn, pq, out, BT);
}

// Round 3
// 101.512 us; speedup vs baseline: 1.1568x; 1.0424x over previous
//
#include <hip/hip_runtime.h>

#define NDEPTH 8
#define DDIM 2048
#define THREADS 512
#define EPS 1e-6f

typedef float f32x4 __attribute__((ext_vector_type(4)));

// One block per (b,t); 512 threads, each owns one float4 slot of the D=2048
// row for all 8 depth entries. V streams through registers exactly once
// (non-temporal). Reduction: value-packed 17-shuffle butterfly -> 16 lanes
// write LDS -> wave 0 computes softmax -> broadcast 8 weights to all threads.
__global__ __launch_bounds__(THREADS)
void block_attn_residual_kernel(const float* __restrict__ V,
                                const float* __restrict__ wn,
                                const float* __restrict__ pq,
                                float* __restrict__ out,
                                int BT) {
    const int bt   = blockIdx.x;
    const int tid  = threadIdx.x;
    const int f    = tid;                 // float4 slot 0..511
    const int wave = tid >> 6;
    const int lane = tid & 63;

    __shared__ __align__(16) float red[16][NDEPTH];  // [value idx][wave]
    __shared__ __align__(16) float wgt8[NDEPTH];     // final softmax weights

    // wq[d] = key_norm_weight[d] * pseudo_query[d]
    const f32x4* w4 = reinterpret_cast<const f32x4*>(wn);
    const f32x4* q4 = reinterpret_cast<const f32x4*>(pq);
    const f32x4 wq = w4[f] * q4[f];

    // V[n,b,t,d] flat index = (n*BT + bt)*D + d
    const f32x4* V4 = reinterpret_cast<const f32x4*>(V) + (size_t)bt * (DDIM / 4);
    const size_t nStride = (size_t)BT * (DDIM / 4);

    f32x4 v[NDEPTH];
    float val[16];     // val[n] = ss[n], val[8+n] = dt[n]

#pragma unroll
    for (int n = 0; n < NDEPTH; ++n) {
        f32x4 x = __builtin_nontemporal_load(&V4[(size_t)n * nStride + f]);
        v[n] = x;
        val[n]     = x[0]*x[0]  + x[1]*x[1]  + x[2]*x[2]  + x[3]*x[3];
        val[n + 8] = x[0]*wq[0] + x[1]*wq[1] + x[2]*wq[2] + x[3]*wq[3];
    }

    // Value-packed butterfly: fold value index into lane index.
    // After rounds O=32,16,8,4 lane l holds value idx (l>>2)&15, partially
    // summed; rounds O=2,1 complete the wave-wide sum. 17 shuffles total.
#pragma unroll
    for (int i = 0; i < 8; ++i) {   // O=32: pairs (i, i+8)
        float a = val[i], b = val[i + 8];
        float x = (lane & 32) ? a : b;
        float y = __shfl_xor(x, 32, 64);
        val[i] = ((lane & 32) ? b : a) + y;
    }
#pragma unroll
    for (int i = 0; i < 4; ++i) {   // O=16: pairs (i, i+4)
        float a = val[i], b = val[i + 4];
        float x = (lane & 16) ? a : b;
        float y = __shfl_xor(x, 16, 64);
        val[i] = ((lane & 16) ? b : a) + y;
    }
#pragma unroll
    for (int i = 0; i < 2; ++i) {   // O=8: pairs (i, i+2)
        float a = val[i], b = val[i + 2];
        float x = (lane & 8) ? a : b;
        float y = __shfl_xor(x, 8, 64);
        val[i] = ((lane & 8) ? b : a) + y;
    }
    {                               // O=4: pair (0, 1)
        float a = val[0], b = val[1];
        float x = (lane & 4) ? a : b;
        float y = __shfl_xor(x, 4, 64);
        val[0] = ((lane & 4) ? b : a) + y;
    }
    float t = val[0];
    t += __shfl_xor(t, 2, 64);
    t += __shfl_xor(t, 1, 64);
    // lane l (within each group of 4) holds wave total of value (l>>2)&15

    if ((lane & 3) == 0) red[(lane >> 2) & 15][wave] = t;
    __syncthreads();

    if (wave == 0) {
        // lanes 0..15: cross-wave sum of one value each
        float tot = 0.0f;
        if (lane < 16) {
            const f32x4* r4 = reinterpret_cast<const f32x4*>(&red[lane][0]);
            f32x4 p = r4[0] + r4[1];
            tot = p[0] + p[1] + p[2] + p[3];
        }
        // lanes 0..7: S[lane]; fetch Dq[lane] from lane+8
        float dq = __shfl(tot, (lane & 7) + 8, 64);
        float rms = rsqrtf(tot * (1.0f / DDIM) + EPS);
        float logit = rms * dq;
        // softmax across lanes 0..7 (width-8 confined; lanes >=8 hold garbage
        // but never escape their group and never write)
        float m = logit;
        m = fmaxf(m, __shfl_xor(m, 1, 8));
        m = fmaxf(m, __shfl_xor(m, 2, 8));
        m = fmaxf(m, __shfl_xor(m, 4, 8));
        float e = __expf(logit - m);
        float s = e;
        s += __shfl_xor(s, 1, 8);
        s += __shfl_xor(s, 2, 8);
        s += __shfl_xor(s, 4, 8);
        if (lane < 8) wgt8[lane] = e / s;
    }
    __syncthreads();

    // broadcast read of the 8 weights (all lanes same address -> free)
    const f32x4* wg4 = reinterpret_cast<const f32x4*>(wgt8);
    const f32x4 wA = wg4[0];
    const f32x4 wB = wg4[1];

    f32x4 o = wA[0] * v[0];
    o += wA[1] * v[1];
    o += wA[2] * v[2];
    o += wA[3] * v[3];
    o += wB[0] * v[4];
    o += wB[1] * v[5];
    o += wB[2] * v[6];
    o += wB[3] * v[7];

    f32x4* out4 = reinterpret_cast<f32x4*>(out) + (size_t)bt * (DDIM / 4);
    __builtin_nontemporal_store(o, &out4[f]);
}

extern "C" void kernel_launch(void* const* d_in, const int* in_sizes, int n_in,
                              void* d_out, int out_size, void* d_ws, size_t ws_size,
                              hipStream_t stream) {
    const float* V  = (const float*)d_in[0];
    const float* wn = (const float*)d_in[1];
    const float* pq = (const float*)d_in[2];
    float* out = (float*)d_out;

    const int BT = in_sizes[0] / (NDEPTH * DDIM);  // B*T
    block_attn_residual_kernel<<<dim3(BT), dim3(THREADS), 0, stream>>>(V, wn, pq, out, BT);
}

// Round 4
// 99.402 us; speedup vs baseline: 1.1813x; 1.0212x over previous
//
#include <hip/hip_runtime.h>

#define NDEPTH 8
#define DDIM 2048
#define THREADS 512
#define EPS 1e-6f

typedef float f32x4 __attribute__((ext_vector_type(4)));

// One block per (b,t); 512 threads, each owns one float4 slot of the D=2048
// row for all 8 depth entries. V streams through registers exactly once
// (non-temporal). Reduction: value-packed 17-shuffle butterfly -> 16 lanes
// write LDS -> ONE barrier -> every wave independently computes cross-wave
// totals + softmax + in-wave weight broadcast (no second barrier).
__global__ __launch_bounds__(THREADS, 4)
void block_attn_residual_kernel(const float* __restrict__ V,
                                const float* __restrict__ wn,
                                const float* __restrict__ pq,
                                float* __restrict__ out,
                                int BT) {
    const int bt   = blockIdx.x;
    const int tid  = threadIdx.x;
    const int f    = tid;                 // float4 slot 0..511
    const int wave = tid >> 6;
    const int lane = tid & 63;

    __shared__ __align__(16) float red[16][NDEPTH];  // [value idx][wave]

    // wq[d] = key_norm_weight[d] * pseudo_query[d]
    const f32x4* w4 = reinterpret_cast<const f32x4*>(wn);
    const f32x4* q4 = reinterpret_cast<const f32x4*>(pq);
    const f32x4 wq = w4[f] * q4[f];

    // V[n,b,t,d] flat index = (n*BT + bt)*D + d
    const f32x4* V4 = reinterpret_cast<const f32x4*>(V) + (size_t)bt * (DDIM / 4);
    const size_t nStride = (size_t)BT * (DDIM / 4);

    f32x4 v[NDEPTH];
    float val[16];     // val[n] = ss[n], val[8+n] = dt[n]

#pragma unroll
    for (int n = 0; n < NDEPTH; ++n) {
        f32x4 x = __builtin_nontemporal_load(&V4[(size_t)n * nStride + f]);
        v[n] = x;
        val[n]     = x[0]*x[0]  + x[1]*x[1]  + x[2]*x[2]  + x[3]*x[3];
        val[n + 8] = x[0]*wq[0] + x[1]*wq[1] + x[2]*wq[2] + x[3]*wq[3];
    }

    // Value-packed butterfly: fold value index into lane index.
    // After rounds O=32,16,8,4 lane l holds value idx (l>>2)&15, partially
    // summed; rounds O=2,1 complete the wave-wide sum. 17 shuffles total.
#pragma unroll
    for (int i = 0; i < 8; ++i) {   // O=32: pairs (i, i+8)
        float a = val[i], b = val[i + 8];
        float x = (lane & 32) ? a : b;
        float y = __shfl_xor(x, 32, 64);
        val[i] = ((lane & 32) ? b : a) + y;
    }
#pragma unroll
    for (int i = 0; i < 4; ++i) {   // O=16: pairs (i, i+4)
        float a = val[i], b = val[i + 4];
        float x = (lane & 16) ? a : b;
        float y = __shfl_xor(x, 16, 64);
        val[i] = ((lane & 16) ? b : a) + y;
    }
#pragma unroll
    for (int i = 0; i < 2; ++i) {   // O=8: pairs (i, i+2)
        float a = val[i], b = val[i + 2];
        float x = (lane & 8) ? a : b;
        float y = __shfl_xor(x, 8, 64);
        val[i] = ((lane & 8) ? b : a) + y;
    }
    {                               // O=4: pair (0, 1)
        float a = val[0], b = val[1];
        float x = (lane & 4) ? a : b;
        float y = __shfl_xor(x, 4, 64);
        val[0] = ((lane & 4) ? b : a) + y;
    }
    float t = val[0];
    t += __shfl_xor(t, 2, 64);
    t += __shfl_xor(t, 1, 64);
    // lane l (within each group of 4) holds wave total of value (l>>2)&15

    if ((lane & 3) == 0) red[(lane >> 2) & 15][wave] = t;
    __syncthreads();   // the ONLY barrier

    // Every wave independently: cross-wave totals (lanes 0..15), softmax,
    // in-wave broadcast of the 8 weights.
    float tot = 0.0f;
    if (lane < 16) {
        const f32x4* r4 = reinterpret_cast<const f32x4*>(&red[lane][0]);
        f32x4 p = r4[0] + r4[1];
        tot = p[0] + p[1] + p[2] + p[3];
    }
    // lanes 0..7: S[lane]; fetch Dq[lane] from lane+8
    float dq = __shfl(tot, (lane & 7) + 8, 64);
    float rms = rsqrtf(tot * (1.0f / DDIM) + EPS);
    float logit = rms * dq;
    // width-8 softmax (lanes >=8 compute garbage that never escapes)
    float m = logit;
    m = fmaxf(m, __shfl_xor(m, 1, 8));
    m = fmaxf(m, __shfl_xor(m, 2, 8));
    m = fmaxf(m, __shfl_xor(m, 4, 8));
    float e = __expf(logit - m);
    float s = e;
    s += __shfl_xor(s, 1, 8);
    s += __shfl_xor(s, 2, 8);
    s += __shfl_xor(s, 4, 8);
    float wfin = e / s;            // lanes 0..7 hold wgt[0..7]

    // broadcast from lanes 0..7 to all 64 lanes
    float w0 = __shfl(wfin, 0, 64);
    float w1 = __shfl(wfin, 1, 64);
    float w2 = __shfl(wfin, 2, 64);
    float w3 = __shfl(wfin, 3, 64);
    float w4b = __shfl(wfin, 4, 64);
    float w5 = __shfl(wfin, 5, 64);
    float w6 = __shfl(wfin, 6, 64);
    float w7 = __shfl(wfin, 7, 64);

    f32x4 o = w0 * v[0];
    o += w1 * v[1];
    o += w2 * v[2];
    o += w3 * v[3];
    o += w4b * v[4];
    o += w5 * v[5];
    o += w6 * v[6];
    o += w7 * v[7];

    f32x4* out4 = reinterpret_cast<f32x4*>(out) + (size_t)bt * (DDIM / 4);
    __builtin_nontemporal_store(o, &out4[f]);
}

extern "C" void kernel_launch(void* const* d_in, const int* in_sizes, int n_in,
                              void* d_out, int out_size, void* d_ws, size_t ws_size,
                              hipStream_t stream) {
    const float* V  = (const float*)d_in[0];
    const float* wn = (const float*)d_in[1];
    const float* pq = (const float*)d_in[2];
    float* out = (float*)d_out;

    const int BT = in_sizes[0] / (NDEPTH * DDIM);  // B*T
    block_attn_residual_kernel<<<dim3(BT), dim3(THREADS), 0, stream>>>(V, wn, pq, out, BT);
}